// Round 13
// baseline (1528.835 us; speedup 1.0000x reference)
//
#include <hip/hip_runtime.h>
#include <hip/hip_bf16.h>
#include <math.h>
#include <stdint.h>

typedef __attribute__((ext_vector_type(8))) short short8;
typedef __attribute__((ext_vector_type(4))) float f32x4;
typedef __attribute__((ext_vector_type(4))) unsigned int uint4v;

#define T_ 512

__device__ __forceinline__ unsigned short bf16rn(float f) {
  union { float f; unsigned u; } x; x.f = f;
  unsigned r = x.u + 0x7FFF + ((x.u >> 16) & 1);
  return (unsigned short)(r >> 16);
}

__device__ __forceinline__ void gload16(const void* gsrc, void* ldst) {
  __builtin_amdgcn_global_load_lds(
      (const __attribute__((address_space(1))) unsigned int*)gsrc,
      (__attribute__((address_space(3))) unsigned int*)ldst, 16, 0, 0);
}

// raw barrier: LDS-visibility only (lgkmcnt), NO vmcnt drain.
__device__ __forceinline__ void wg_barrier() {
  __builtin_amdgcn_sched_barrier(0);
  asm volatile("s_waitcnt lgkmcnt(0)" ::: "memory");
  __builtin_amdgcn_sched_barrier(0);
  __builtin_amdgcn_s_barrier();
  __builtin_amdgcn_sched_barrier(0);
}

// ---------------- conv1 + pool (fp32 math, bf16 out), 8 frames/block ----------------
__global__ __launch_bounds__(256) void conv1_kernel(
    const float* __restrict__ phone, const float* __restrict__ w1,
    const float* __restrict__ b1, ushort* __restrict__ out1b) {
  __shared__ float ws[128 * 77];
  __shared__ float bs[128];
  __shared__ float xs[8][7][52];
  const int tid = threadIdx.x;
  const int n0 = blockIdx.x * 8;
  for (int idx = tid; idx < 9856; idx += 256) ws[idx] = w1[idx];
  if (tid < 128) bs[tid] = b1[tid];
  for (int idx = tid; idx < 2800; idx += 256) {
    int fi = idx / 350, r = idx - fi * 350;
    int ll = r / 7, c = r - ll * 7;
    xs[fi][c][ll] = phone[(size_t)(n0 + fi) * 350 + r];
  }
  __syncthreads();

  const int o = tid >> 1, ph = tid & 1;
  const float* wo = ws + o * 77;
  const float bb = bs[o];
  for (int fi = 0; fi < 8; ++fi) {
    float acc0[10], acc1[10];
#pragma unroll
    for (int q = 0; q < 10; ++q) { acc0[q] = 0.f; acc1[q] = 0.f; }
    for (int i = 0; i < 7; ++i) {
      float wr[11];
#pragma unroll
      for (int k = 0; k < 11; ++k) wr[k] = wo[i * 11 + k];
#pragma unroll
      for (int q = 0; q < 10; ++q) {
        int p = ph * 10 + q;
        int base = 2 * p;
        float xv[12];
#pragma unroll
        for (int j = 0; j < 12; ++j) xv[j] = xs[fi][i][base + j];
        float s0 = 0.f, s1 = 0.f;
#pragma unroll
        for (int k = 0; k < 11; ++k) {
          s0 += xv[k] * wr[k];
          s1 += xv[k + 1] * wr[k];
        }
        acc0[q] += s0;
        acc1[q] += s1;
      }
    }
#pragma unroll
    for (int q = 0; q < 10; ++q) {
      int p = ph * 10 + q;
      out1b[((size_t)(n0 + fi) * 128 + o) * 20 + p] =
          bf16rn(fmaxf(acc0[q], acc1[q]) + bb);
    }
  }
}

// ---------------- merged fp32 -> bf16 converts (4 weight tensors, 1 launch) ----------------
__global__ __launch_bounds__(256) void f32_to_bf16_multi(
    const float* __restrict__ s0, ushort* __restrict__ d0,
    const float* __restrict__ s1, ushort* __restrict__ d1,
    const float* __restrict__ s2, ushort* __restrict__ d2,
    const float* __restrict__ s3, ushort* __restrict__ d3) {
  const int n0 = 73728, n1 = 393216, n2 = 131072, n3 = 196608;
  int i = blockIdx.x * 256 + threadIdx.x;
  const float* s; ushort* d; int off;
  if (i < n0) { s = s0; d = d0; off = i; }
  else if (i < n0 + n1) { s = s1; d = d1; off = i - n0; }
  else if (i < n0 + n1 + n2) { s = s2; d = d2; off = i - n0 - n1; }
  else if (i < n0 + n1 + n2 + n3) { s = s3; d = d3; off = i - n0 - n1 - n2; }
  else return;
  float4 v = ((const float4*)s)[off];
  ushort4 o;
  o.x = bf16rn(v.x); o.y = bf16rn(v.y); o.z = bf16rn(v.z); o.w = bf16rn(v.w);
  ((ushort4*)d)[off] = o;
}

// ---------------- stage h0 -> tagged fragments, 4 groups, parity 0, tag 0 ----------------
// hxt (8B words): [group(4)][parity(2)][frag s<16][word w<64]
//   w = (fqk*4 + b4)*4 + p2;  D = s*32 + fqk*8 + p2*2; batch = g*4 + b4
__global__ __launch_bounds__(256) void stage_h0(
    const float* __restrict__ h0, unsigned long long* __restrict__ hxt) {
  const int tid = threadIdx.x;
#pragma unroll
  for (int k = 0; k < 16; ++k) {
    int idx = tid + k * 256;             // 0..4095
    int g = idx >> 10, rem = idx & 1023;
    int s = rem >> 6, w = rem & 63;
    int b4 = (w >> 2) & 3, fqk = w >> 4, p2 = w & 3;
    int b = g * 4 + b4;
    int D = s * 32 + fqk * 8 + p2 * 2;
    float2 h2 = *(const float2*)(h0 + (size_t)b * 512 + D);
    unsigned pk = (unsigned)bf16rn(h2.x) | ((unsigned)bf16rn(h2.y) << 16);
    hxt[(size_t)g * 2048 + rem] = (unsigned long long)pk;  // tag 0
  }
}

// ---------------- bf16 MFMA GEMM: C = A @ W^T + bias ----------------
template <int AM, int EM>
__global__ __launch_bounds__(256) void gemm_bf16(
    const ushort* __restrict__ A, const ushort* __restrict__ W,
    const float* __restrict__ bias, void* __restrict__ Cout,
    int K, int lda, int ldc) {
  __shared__ ushort As[128 * 64];
  __shared__ ushort Bs[128 * 64];
  __shared__ ushort tbl[1152];
  const int tid = threadIdx.x;
  const int l = tid & 63, wv = tid >> 6;
  const int wr = wv >> 1, wc = wv & 1;
  const int fr = l & 15, fq = l >> 4;
  const int bm0 = blockIdx.x * 128, bn0 = blockIdx.y * 128;

  if (AM == 1) {
    for (int idx = tid; idx < 1152; idx += 256) {
      int i2 = idx / 9, kp = idx - i2 * 9;
      tbl[idx] = (ushort)(i2 * 20 + kp);
    }
    __syncthreads();
  }

  f32x4 acc[4][4];
#pragma unroll
  for (int mi = 0; mi < 4; ++mi)
#pragma unroll
    for (int ni = 0; ni < 4; ++ni) acc[mi][ni] = (f32x4)0.f;

  const int pr8 = l >> 3;
  const int pc = l & 7;
  const int nkt = K >> 6;
  for (int kt = 0; kt < nkt; ++kt) {
    const int k0 = kt << 6;
#pragma unroll
    for (int i = 0; i < 4; ++i) {
      int q = wv * 4 + i;
      int prow = q * 8 + pr8;
      int lc = pc ^ (prow & 7);
      gload16(W + (size_t)(bn0 + prow) * K + k0 + lc * 8, &Bs[q * 512]);
    }
    if (AM == 0) {
#pragma unroll
      for (int i = 0; i < 4; ++i) {
        int q = wv * 4 + i;
        int prow = q * 8 + pr8;
        int lc = pc ^ (prow & 7);
        gload16(A + (size_t)(bm0 + prow) * lda + k0 + lc * 8, &As[q * 512]);
      }
    } else {
#pragma unroll
      for (int q = 0; q < 16; ++q) {
        int idx = tid + q * 256;
        int row = idx >> 5, c0 = (idx & 31) * 2;
        int m = bm0 + row;
        int n = m / 12, pos = m - n * 12;
        int kk = k0 + c0;
        const ushort* an = A + (size_t)n * 2560 + pos;
        uint e0 = an[tbl[kk]];
        uint e1 = an[tbl[kk + 1]];
        *(uint*)&As[row * 64 + (((c0 >> 3) ^ (row & 7)) << 3) + (c0 & 7)] =
            e0 | (e1 << 16);
      }
    }
    __syncthreads();
#pragma unroll
    for (int ks = 0; ks < 2; ++ks) {
      short8 af[4], bfr[4];
#pragma unroll
      for (int mi = 0; mi < 4; ++mi) {
        int row = wr * 64 + mi * 16 + fr;
        af[mi] = *(const short8*)&As[row * 64 + (((ks * 4 + fq) ^ (row & 7)) << 3)];
      }
#pragma unroll
      for (int ni = 0; ni < 4; ++ni) {
        int row = wc * 64 + ni * 16 + fr;
        bfr[ni] = *(const short8*)&Bs[row * 64 + (((ks * 4 + fq) ^ (row & 7)) << 3)];
      }
#pragma unroll
      for (int mi = 0; mi < 4; ++mi)
#pragma unroll
        for (int ni = 0; ni < 4; ++ni)
          acc[mi][ni] = __builtin_amdgcn_mfma_f32_16x16x32_bf16(
              af[mi], bfr[ni], acc[mi][ni], 0, 0, 0);
    }
    __syncthreads();
  }

#pragma unroll
  for (int ni = 0; ni < 4; ++ni) {
    int col = bn0 + wc * 64 + ni * 16 + fr;
    float bv = bias[col];
#pragma unroll
    for (int mi = 0; mi < 4; ++mi) {
      int mbase = bm0 + wr * 64 + mi * 16 + fq * 4;
      if (EM == 0) {
        ushort* C = (ushort*)Cout;
#pragma unroll
        for (int j = 0; j < 4; ++j)
          C[(size_t)(mbase + j) * ldc + col] = bf16rn(acc[mi][ni][j] + bv);
      } else if (EM == 1) {
        ushort* C = (ushort*)Cout;
#pragma unroll
        for (int j = 0; j < 4; j += 2) {
          int m = mbase + j;
          int n = m / 12, pos = m - n * 12;
          float v = fmaxf(acc[mi][ni][j], acc[mi][ni][j + 1]) + bv;
          C[(size_t)n * 1536 + col * 6 + (pos >> 1)] = bf16rn(v);
        }
      } else {
        float* C = (float*)Cout;
#pragma unroll
        for (int j = 0; j < 4; ++j) {
          int m = mbase + j;
          int b = m >> 9, tt = m & 511;
          C[((size_t)tt * 16 + b) * 1536 + col] = acc[mi][ni][j] + bv;
        }
      }
    }
  }
}

// ---------------- persistent GRU: 4 independent groups x 4 WGs (batch-split) ----------------
// Group g = blockIdx>>2 handles batch [4g, 4g+4); member wp = blockIdx&3 owns
// h-dims [wp*128, wp*128+128) for all 3 gates (384 rows = 24 tiles; 8 waves x
// 3 tiles, 512 thr).  MFMA M=4 (A rows 4..15 zero).  Exchange: r12-proven
// tagged 8B protocol among the 4 group members; 8KB/parity/group.
__global__ __launch_bounds__(512) void gru_persistent(
    const float* __restrict__ h0, const float* __restrict__ gi,
    const float* __restrict__ whh, const float* __restrict__ bhh,
    float* __restrict__ hsbuf, unsigned long long* __restrict__ hxt) {
  __shared__ float gh_lds[24 * 64];      // [tile][row4][col16]
  __shared__ unsigned afl[16 * 64 * 4];  // 16KB A-fragments (rows>=4 zero)
  const int tid = threadIdx.x;
  const int g = blockIdx.x >> 2, wp = blockIdx.x & 3;
  const int l = tid & 63, v = tid >> 6;  // wave 0..7
  const int fr = l & 15, fq = l >> 4;
  unsigned long long* hxg = hxt + (size_t)g * 2048;

  // zero afl (unused rows stay 0 forever)
  for (int i = tid; i < 4096; i += 512) afl[i] = 0u;

  // persistent Whh B-fragments: 3 tiles/wave (192 regs of weights)
  const int tA = 3 * v, tB = 3 * v + 1, tC = 3 * v + 2;
  const int oA = (tA >> 3) * 512 + wp * 128 + (tA & 7) * 16 + fr;
  const int oB = (tB >> 3) * 512 + wp * 128 + (tB & 7) * 16 + fr;
  const int oC = (tC >> 3) * 512 + wp * 128 + (tC & 7) * 16 + fr;
  short8 bfA[16], bfB[16], bfC[16];
#pragma unroll
  for (int s = 0; s < 16; ++s) {
    const float* pA = whh + (size_t)oA * 512 + s * 32 + fq * 8;
    const float* pB = whh + (size_t)oB * 512 + s * 32 + fq * 8;
    const float* pC = whh + (size_t)oC * 512 + s * 32 + fq * 8;
    float4 a0 = *(const float4*)pA, a1 = *(const float4*)(pA + 4);
    float4 b0 = *(const float4*)pB, b1 = *(const float4*)(pB + 4);
    float4 c0 = *(const float4*)pC, c1 = *(const float4*)(pC + 4);
    short8 x, y, z;
    x[0] = (short)bf16rn(a0.x); x[1] = (short)bf16rn(a0.y);
    x[2] = (short)bf16rn(a0.z); x[3] = (short)bf16rn(a0.w);
    x[4] = (short)bf16rn(a1.x); x[5] = (short)bf16rn(a1.y);
    x[6] = (short)bf16rn(a1.z); x[7] = (short)bf16rn(a1.w);
    y[0] = (short)bf16rn(b0.x); y[1] = (short)bf16rn(b0.y);
    y[2] = (short)bf16rn(b0.z); y[3] = (short)bf16rn(b0.w);
    y[4] = (short)bf16rn(b1.x); y[5] = (short)bf16rn(b1.y);
    y[6] = (short)bf16rn(b1.z); y[7] = (short)bf16rn(b1.w);
    z[0] = (short)bf16rn(c0.x); z[1] = (short)bf16rn(c0.y);
    z[2] = (short)bf16rn(c0.z); z[3] = (short)bf16rn(c0.w);
    z[4] = (short)bf16rn(c1.x); z[5] = (short)bf16rn(c1.y);
    z[6] = (short)bf16rn(c1.z); z[7] = (short)bf16rn(c1.w);
    bfA[s] = x; bfB[s] = y; bfC[s] = z;
  }
  const float boA = bhh[oA], boB = bhh[oB], boC = bhh[oC];

  // gate threads (tid<256): batch b4 = tid>>6, pair jp = tid&63 -> dims (jl, jl+1)
  const int b4 = tid >> 6, jp = tid & 63, jl = jp * 2;
  const bool gthr = (tid < 256);
  const bool pthr = (tid >= 256 && tid < 384);   // poller waves 4-5
  const int pt = tid - 256;
  const int bglob = g * 4 + (b4 & 3);
  const int jglob = wp * 128 + jl;
  float hA = 0.f, hB = 0.f;
  float giC0 = 0.f, giC1 = 0.f, giC2 = 0.f, giC3 = 0.f, giC4 = 0.f, giC5 = 0.f;
  float giN0 = 0.f, giN1 = 0.f, giN2 = 0.f, giN3 = 0.f, giN4 = 0.f, giN5 = 0.f;
  if (gthr) {
    float2 h2 = *(const float2*)(h0 + (size_t)bglob * 512 + jglob);
    hA = h2.x; hB = h2.y;
    const float* g0 = gi + (size_t)bglob * 1536 + jglob;             // gi[0]
    float2 r0 = *(const float2*)(g0);
    float2 r1 = *(const float2*)(g0 + 512);
    float2 r2 = *(const float2*)(g0 + 1024);
    giC0 = r0.x; giC3 = r0.y; giC1 = r1.x; giC4 = r1.y; giC2 = r2.x; giC5 = r2.y;
    const float* g1 = gi + (size_t)(16 + bglob) * 1536 + jglob;      // gi[1]
    float2 s0 = *(const float2*)(g1);
    float2 s1 = *(const float2*)(g1 + 512);
    float2 s2 = *(const float2*)(g1 + 1024);
    giN0 = s0.x; giN3 = s0.y; giN1 = s1.x; giN4 = s1.y; giN2 = s2.x; giN5 = s2.y;
  }
  __syncthreads();   // afl zero-init visible before deposits

  // ---- prologue: pollers fetch h_0 (parity 0, tag 0) ----
  if (pthr) {
    const int ps = pt >> 3;              // frag 0..15
    const int w0 = (pt & 7) * 8;         // word base within frag
    const unsigned long long* base = hxg + ps * 64 + w0;
    uint4v r[4];
    for (;;) {
#pragma unroll
      for (int q = 0; q < 4; ++q)
        asm volatile("global_load_dwordx4 %0, %1, off sc0 sc1"
                     : "=v"(r[q]) : "v"(base + q * 2));
      asm volatile("s_waitcnt vmcnt(0)" ::: "memory");
      __builtin_amdgcn_sched_barrier(0);
      bool ok = true;
#pragma unroll
      for (int q = 0; q < 4; ++q)
        ok = ok & (r[q].y == 0u) & (r[q].w == 0u);
      if (ok) break;
    }
#pragma unroll
    for (int q = 0; q < 4; ++q) {
      int w = w0 + 2 * q;
      int lane = ((w >> 2) & 3) | ((w >> 4) << 4);
      *(uint2*)&afl[(ps * 64 + lane) * 4 + (w & 3)] = make_uint2(r[q].x, r[q].z);
    }
  }
  wg_barrier();

  for (int t = 0; t < T_; ++t) {
    // ---- phase 1: all 8 waves MFMA gh = h_t @ Whh^T (3 tiles/wave) ----
    f32x4 aA = (f32x4)0.f, aB = (f32x4)0.f, aC = (f32x4)0.f;
#pragma unroll
    for (int s = 0; s < 16; ++s) {
      union { uint4v u; short8 s8; } ca;
      ca.u = *(const uint4v*)&afl[(s * 64 + l) * 4];
      aA = __builtin_amdgcn_mfma_f32_16x16x32_bf16(ca.s8, bfA[s], aA, 0, 0, 0);
      aB = __builtin_amdgcn_mfma_f32_16x16x32_bf16(ca.s8, bfB[s], aB, 0, 0, 0);
      aC = __builtin_amdgcn_mfma_f32_16x16x32_bf16(ca.s8, bfC[s], aC, 0, 0, 0);
    }
    if (fq == 0) {
#pragma unroll
      for (int j = 0; j < 4; ++j) {
        gh_lds[tA * 64 + j * 16 + fr] = aA[j] + boA;
        gh_lds[tB * 64 + j * 16 + fr] = aB[j] + boB;
        gh_lds[tC * 64 + j * 16 + fr] = aC[j] + boC;
      }
    }
    wg_barrier();

    // ---- phase 2: gates+store (waves 0-3) || poll t+1 (waves 4-5) ----
    if (gthr) {
      const int tl = jl >> 4, c = jl & 15;
      float2 rr = *(const float2*)&gh_lds[(0 + tl) * 64 + b4 * 16 + c];
      float2 zz = *(const float2*)&gh_lds[(8 + tl) * 64 + b4 * 16 + c];
      float2 nn = *(const float2*)&gh_lds[(16 + tl) * 64 + b4 * 16 + c];
      float rgA = __builtin_amdgcn_rcpf(1.f + __expf(-(giC0 + rr.x)));
      float rgB = __builtin_amdgcn_rcpf(1.f + __expf(-(giC3 + rr.y)));
      float zgA = __builtin_amdgcn_rcpf(1.f + __expf(-(giC1 + zz.x)));
      float zgB = __builtin_amdgcn_rcpf(1.f + __expf(-(giC4 + zz.y)));
      float eA = __expf(2.f * (giC2 + rgA * nn.x));
      float eB = __expf(2.f * (giC5 + rgB * nn.y));
      float ngA = 1.f - 2.f * __builtin_amdgcn_rcpf(eA + 1.f);
      float ngB = 1.f - 2.f * __builtin_amdgcn_rcpf(eB + 1.f);
      hA = (1.f - zgA) * ngA + zgA * hA;
      hB = (1.f - zgB) * ngB + zgB * hB;
      // tagged 8B agent store = data + release flag in one transaction
      if (t + 1 < T_) {
        unsigned pk = (unsigned)bf16rn(hA) | ((unsigned)bf16rn(hB) << 16);
        unsigned long long payload =
            (unsigned long long)pk | ((unsigned long long)(unsigned)(t + 1) << 32);
        int s = wp * 4 + (jl >> 5);
        int w_i = (((jl >> 3) & 3) * 4 + b4) * 4 + ((jl & 7) >> 1);
        __hip_atomic_store(hxg + ((t + 1) & 1) * 1024 + s * 64 + w_i, payload,
                           __ATOMIC_RELAXED, __HIP_MEMORY_SCOPE_AGENT);
      }
      // off-critical-path: fp32 h for fc3; shift gi pipeline; prefetch gi[t+2]
      *(float2*)(hsbuf + ((size_t)t * 16 + bglob) * 512 + jglob) =
          make_float2(hA, hB);
      giC0 = giN0; giC1 = giN1; giC2 = giN2;
      giC3 = giN3; giC4 = giN4; giC5 = giN5;
      if (t + 2 < T_) {
        const float* gb = gi + ((size_t)(t + 2) * 16 + bglob) * 1536 + jglob;
        float2 r0 = *(const float2*)(gb);
        float2 r1 = *(const float2*)(gb + 512);
        float2 r2 = *(const float2*)(gb + 1024);
        giN0 = r0.x; giN3 = r0.y; giN1 = r1.x; giN4 = r1.y; giN2 = r2.x; giN5 = r2.y;
      }
    } else if (pthr && t + 1 < T_) {
      const int ps = pt >> 3;
      const int w0 = (pt & 7) * 8;
      const unsigned long long* base =
          hxg + ((t + 1) & 1) * 1024 + ps * 64 + w0;
      const unsigned tag = (unsigned)(t + 1);
      uint4v r[4];
      for (;;) {
#pragma unroll
        for (int q = 0; q < 4; ++q)
          asm volatile("global_load_dwordx4 %0, %1, off sc0 sc1"
                       : "=v"(r[q]) : "v"(base + q * 2));
        asm volatile("s_waitcnt vmcnt(0)" ::: "memory");
        __builtin_amdgcn_sched_barrier(0);
        bool ok = true;
#pragma unroll
        for (int q = 0; q < 4; ++q)
          ok = ok & (r[q].y == tag) & (r[q].w == tag);
        if (ok) break;
      }
#pragma unroll
      for (int q = 0; q < 4; ++q) {
        int w = w0 + 2 * q;
        int lane = ((w >> 2) & 3) | ((w >> 4) << 4);
        *(uint2*)&afl[(ps * 64 + lane) * 4 + (w & 3)] = make_uint2(r[q].x, r[q].z);
      }
    }
    wg_barrier();
  }
}

// ---------------- fc3 ----------------
__global__ __launch_bounds__(256) void fc3_kernel(
    const float* __restrict__ hs, const float* __restrict__ w3,
    const float* __restrict__ b3, float* __restrict__ out) {
  __shared__ float w[512];
  const int tid = threadIdx.x;
  w[tid] = w3[tid];
  w[tid + 256] = w3[tid + 256];
  __syncthreads();
  const int gidx = blockIdx.x * 256 + tid;  // b*512 + t
  const int b = gidx >> 9, t = gidx & 511;
  const float4* hr = (const float4*)(hs + ((size_t)t * 16 + b) * 512);
  const float4* wr = (const float4*)w;
  float acc = 0.f;
#pragma unroll 8
  for (int kc = 0; kc < 128; ++kc) {
    float4 h = hr[kc], ww = wr[kc];
    acc += h.x * ww.x + h.y * ww.y + h.z * ww.z + h.w * ww.w;
  }
  out[gidx] = acc + b3[0];
}

// ---------------------------------------------------------------------------
extern "C" void kernel_launch(void* const* d_in, const int* in_sizes, int n_in,
                              void* d_out, int out_size, void* d_ws,
                              size_t ws_size, hipStream_t stream) {
  const float* phone = (const float*)d_in[0];
  const float* h0    = (const float*)d_in[1];
  const float* w1    = (const float*)d_in[2];
  const float* b1    = (const float*)d_in[3];
  const float* w2    = (const float*)d_in[4];
  const float* b2    = (const float*)d_in[5];
  const float* fc1w  = (const float*)d_in[6];
  const float* fc1b  = (const float*)d_in[7];
  const float* fc2w  = (const float*)d_in[8];
  const float* fc2b  = (const float*)d_in[9];
  const float* wih   = (const float*)d_in[10];
  const float* whh   = (const float*)d_in[11];
  const float* bih   = (const float*)d_in[12];
  const float* bhh   = (const float*)d_in[13];
  const float* w3    = (const float*)d_in[14];
  const float* b3    = (const float*)d_in[15];
  float* out = (float*)d_out;

  char* ws = (char*)d_ws;
  ushort* out1b = (ushort*)(ws + 0);            // 41,943,040
  ushort* feat2 = (ushort*)(ws + 41943040);     // 25,165,824
  ushort* feat3 = (ushort*)(ws + 67108864);     // 16,777,216 (dead after fc2)
  ushort* feat4 = (ushort*)(ws + 83886080);     //  8,388,608
  float*  gibuf = (float*) (ws + 92274688);     // 50,331,648  [t][b][1536]
  float*  hsbuf = (float*) (ws + 142606336);    // 16,777,216  [t][b][512]
  ushort* w2b   = (ushort*)(ws + 159383552);    //    589,824
  ushort* fc1wb = (ushort*)(ws + 159973376);    //  3,145,728
  ushort* fc2wb = (ushort*)(ws + 163119104);    //  1,048,576
  ushort* wihb  = (ushort*)(ws + 164167680);    //  1,572,864
  // tagged h-exchange: 4 groups x 2 parities x 8KB = 64KB (dead feat3 region)
  unsigned long long* hxt = (unsigned long long*)(ws + 67108864);

  f32_to_bf16_multi<<<3104, 256, 0, stream>>>(w2, w2b, fc1w, fc1wb,
                                              fc2w, fc2wb, wih, wihb);

  conv1_kernel<<<1024, 256, 0, stream>>>(phone, w1, b1, out1b);
  gemm_bf16<1, 1><<<dim3(768, 2), 256, 0, stream>>>(out1b, w2b, b2, feat2, 1152, 0, 0);
  gemm_bf16<0, 0><<<dim3(64, 8), 256, 0, stream>>>(feat2, fc1wb, fc1b, feat3, 1536, 1536, 1024);
  gemm_bf16<0, 0><<<dim3(64, 4), 256, 0, stream>>>(feat3, fc2wb, fc2b, feat4, 1024, 1024, 512);
  gemm_bf16<0, 2><<<dim3(64, 12), 256, 0, stream>>>(feat4, wihb, bih, gibuf, 512, 512, 1536);

  // clear all tag buffers (replay-safe), stage h0, run recurrence
  hipMemsetAsync(hxt, 0, 65536, stream);
  stage_h0<<<1, 256, 0, stream>>>(h0, hxt);
  gru_persistent<<<16, 512, 0, stream>>>(h0, gibuf, whh, bhh, hsbuf, hxt);

  fc3_kernel<<<32, 256, 0, stream>>>(hsbuf, w3, b3, out);
}